// Round 1
// baseline (491.140 us; speedup 1.0000x reference)
//
#include <hip/hip_runtime.h>
#include <math.h>

// NeighborlistVerletNsq: N=4096 particles, P = N(N-1)/2 pairs.
// Outputs (flattened float32, in return order):
//   [0   , 4P ) pairs  [2,2P]: row0 = concat(i,j), row1 = concat(j,i)
//   [4P  , 6P ) d_full [2P,1]: concat(d_m, d_m)
//   [6P  , 12P) r_full [2P,3]: concat(r_m, -r_m), row-major
//   [12P , 14P) mask   [2P]  : concat(mask, mask) as 0/1
//
// R6: keep R5's analytic (i,j) inversion (no 67 MB index read), but move from
// 1 pair/thread with 14 scalar dword stores to 4 pairs/thread so every output
// stream is written with one aligned float4 (global_store_dwordx4, 16 B/lane
// = the measured-coalescing sweet spot). The f64 sqrt for the triu inversion
// and the pos[i] row load are amortized 4x. Scalar-store fallback covers
// P % 4 != 0 and the grid tail. Fallback kernel reads indices if
// P != N(N-1)/2.
//
// Numerics (exact numpy match, verified absmax 0.0 through R5 — unchanged):
//   remainder(t,L) for t in (-L,2L):  t>=L -> t-L (Sterbenz-exact == fmod);
//   t<0 -> t+L (same single rounding as numpy's fixup); else t.
//   norm: no-fma ((x*x + y*y) + z*z), IEEE sqrtf.

#define CUTOFF_F 0.5f
#define BLOCK 256
#define PPT 4

__device__ __forceinline__ float pbc_wrap_fast(float r, float L, float h) {
    float t = __fadd_rn(r, h);
    float m = (t >= L) ? __fsub_rn(t, L)
            : (t < 0.0f ? __fadd_rn(t, L) : t);
    return __fsub_rn(m, h);
}

// distance + mask from preloaded positions (identical numerics to R5)
__device__ __forceinline__ void compute_pair_pp(float pix, float piy, float piz,
                                                float pjx, float pjy, float pjz,
                                                float Lx, float Ly, float Lz,
                                                float hx, float hy, float hz,
                                                float& dm,
                                                float& mx, float& my, float& mz,
                                                float& mk) {
    float rx = __fsub_rn(pix, pjx);
    float ry = __fsub_rn(piy, pjy);
    float rz = __fsub_rn(piz, pjz);

    rx = pbc_wrap_fast(rx, Lx, hx);
    ry = pbc_wrap_fast(ry, Ly, hy);
    rz = pbc_wrap_fast(rz, Lz, hz);

    float d2 = __fadd_rn(__fadd_rn(__fmul_rn(rx, rx), __fmul_rn(ry, ry)),
                         __fmul_rn(rz, rz));
    float d = sqrtf(d2);

    const bool keep = (d <= CUTOFF_F);
    dm = keep ? d  : 0.0f;
    mx = keep ? rx : 0.0f;
    my = keep ? ry : 0.0f;
    mz = keep ? rz : 0.0f;
    mk = keep ? 1.0f : 0.0f;
}

__device__ __forceinline__ void write_pair(float* __restrict__ out, long long P,
                                           long long p, float fi, float fj,
                                           float dm, float mx, float my,
                                           float mz, float mk) {
    out[p]          = fi;
    out[P + p]      = fj;
    out[2 * P + p]  = fj;
    out[3 * P + p]  = fi;
    out[4 * P + p]  = dm;
    out[5 * P + p]  = dm;
    long long b0 = 6 * P + 3 * p;
    out[b0 + 0] = mx;  out[b0 + 1] = my;  out[b0 + 2] = mz;
    long long b1 = 6 * P + 3 * (P + p);
    out[b1 + 0] = -mx; out[b1 + 1] = -my; out[b1 + 2] = -mz;
    out[12 * P + p] = mk;
    out[13 * P + p] = mk;
}

// offset of first pair in row i: f(i) = i*(2N-1-i)/2  (values non-negative;
// unsigned shift avoids the signed-div fixup)
__device__ __forceinline__ long long row_off(long long i, long long N) {
    return (long long)(((unsigned long long)i *
                        (unsigned long long)(2 * N - 1 - i)) >> 1);
}

__global__ __launch_bounds__(BLOCK)
void nl_nsq_analytic4(const float* __restrict__ pos,
                      const float* __restrict__ box,
                      float*       __restrict__ out,
                      long long P, int N) {
    const long long t  = (long long)blockIdx.x * BLOCK + threadIdx.x;
    const long long p0 = t * PPT;
    if (p0 >= P) return;

    // invert triu_indices at p0: i = floor((2N-1 - sqrt((2N-1)^2 - 8p)) / 2)
    const double twoNm1 = (double)(2 * N - 1);
    const double D = twoNm1 * twoNm1 - 8.0 * (double)p0;
    long long i64 = (long long)((twoNm1 - sqrt(D)) * 0.5);
    if (i64 < 0) i64 = 0;
    if (i64 > N - 2) i64 = N - 2;
    // exact integer fixup (at most 1-2 steps)
    while (row_off(i64 + 1, N) <= p0) ++i64;
    while (row_off(i64, N) > p0) --i64;
    int i = (int)i64;
    int j = (int)(p0 - row_off(i64, N) + i64 + 1);

    const float Lx = box[0], Ly = box[4], Lz = box[8];
    const float hx = Lx * 0.5f, hy = Ly * 0.5f, hz = Lz * 0.5f;

    const int nPairs = (int)((P - p0 < (long long)PPT) ? (P - p0)
                                                       : (long long)PPT);

    float pix = pos[3 * i + 0], piy = pos[3 * i + 1], piz = pos[3 * i + 2];

    float fi[PPT], fj[PPT], dm[PPT], mx[PPT], my[PPT], mz[PPT], mk[PPT];

#pragma unroll
    for (int q = 0; q < PPT; ++q) {
        if (q < nPairs) {
            float pjx = pos[3 * j + 0];
            float pjy = pos[3 * j + 1];
            float pjz = pos[3 * j + 2];
            compute_pair_pp(pix, piy, piz, pjx, pjy, pjz,
                            Lx, Ly, Lz, hx, hy, hz,
                            dm[q], mx[q], my[q], mz[q], mk[q]);
            fi[q] = (float)i;
            fj[q] = (float)j;
            if (q + 1 < nPairs) {           // advance to next pair
                if (++j >= N) {
                    ++i; j = i + 1;         // row crossing (rare: ~1/row_len)
                    pix = pos[3 * i + 0];
                    piy = pos[3 * i + 1];
                    piz = pos[3 * i + 2];
                }
            }
        } else {
            fi[q] = fj[q] = dm[q] = mx[q] = my[q] = mz[q] = mk[q] = 0.0f;
        }
    }

    if (nPairs == PPT && (P & 3LL) == 0LL) {
        // all stream bases 16B-aligned: p0%4==0, P%4==0 => (k*P+p0)%4==0,
        // (6P+3p0)%4==0, (9P+3p0)%4==0
        *reinterpret_cast<float4*>(out + p0)
            = make_float4(fi[0], fi[1], fi[2], fi[3]);
        *reinterpret_cast<float4*>(out + P + p0)
            = make_float4(fj[0], fj[1], fj[2], fj[3]);
        *reinterpret_cast<float4*>(out + 2 * P + p0)
            = make_float4(fj[0], fj[1], fj[2], fj[3]);
        *reinterpret_cast<float4*>(out + 3 * P + p0)
            = make_float4(fi[0], fi[1], fi[2], fi[3]);
        *reinterpret_cast<float4*>(out + 4 * P + p0)
            = make_float4(dm[0], dm[1], dm[2], dm[3]);
        *reinterpret_cast<float4*>(out + 5 * P + p0)
            = make_float4(dm[0], dm[1], dm[2], dm[3]);
        const long long b0 = 6 * P + 3 * p0;
        *reinterpret_cast<float4*>(out + b0 + 0)
            = make_float4(mx[0], my[0], mz[0], mx[1]);
        *reinterpret_cast<float4*>(out + b0 + 4)
            = make_float4(my[1], mz[1], mx[2], my[2]);
        *reinterpret_cast<float4*>(out + b0 + 8)
            = make_float4(mz[2], mx[3], my[3], mz[3]);
        const long long b1 = 6 * P + 3 * (P + p0);
        *reinterpret_cast<float4*>(out + b1 + 0)
            = make_float4(-mx[0], -my[0], -mz[0], -mx[1]);
        *reinterpret_cast<float4*>(out + b1 + 4)
            = make_float4(-my[1], -mz[1], -mx[2], -my[2]);
        *reinterpret_cast<float4*>(out + b1 + 8)
            = make_float4(-mz[2], -mx[3], -my[3], -mz[3]);
        *reinterpret_cast<float4*>(out + 12 * P + p0)
            = make_float4(mk[0], mk[1], mk[2], mk[3]);
        *reinterpret_cast<float4*>(out + 13 * P + p0)
            = make_float4(mk[0], mk[1], mk[2], mk[3]);
    } else {
        for (int q = 0; q < nPairs; ++q) {
            write_pair(out, P, p0 + q, fi[q], fj[q],
                       dm[q], mx[q], my[q], mz[q], mk[q]);
        }
    }
}

__global__ __launch_bounds__(BLOCK)
void nl_nsq_loadidx(const float* __restrict__ pos,
                    const float* __restrict__ box,
                    const int*   __restrict__ ip,
                    const int*   __restrict__ jp,
                    float*       __restrict__ out,
                    long long P) {
    const long long p = (long long)blockIdx.x * BLOCK + threadIdx.x;
    if (p >= P) return;

    const int i = ip[p];
    const int j = jp[p];

    const float Lx = box[0], Ly = box[4], Lz = box[8];
    const float hx = Lx * 0.5f, hy = Ly * 0.5f, hz = Lz * 0.5f;

    float dm, mx, my, mz, mk;
    compute_pair_pp(pos[3 * i + 0], pos[3 * i + 1], pos[3 * i + 2],
                    pos[3 * j + 0], pos[3 * j + 1], pos[3 * j + 2],
                    Lx, Ly, Lz, hx, hy, hz, dm, mx, my, mz, mk);
    write_pair(out, P, p, (float)i, (float)j, dm, mx, my, mz, mk);
}

extern "C" void kernel_launch(void* const* d_in, const int* in_sizes, int n_in,
                              void* d_out, int out_size, void* d_ws, size_t ws_size,
                              hipStream_t stream) {
    const float* pos = (const float*)d_in[0];  // [N,3]
    const float* box = (const float*)d_in[1];  // [3,3]
    const int*   ip  = (const int*)d_in[2];    // [P]
    const int*   jp  = (const int*)d_in[3];    // [P]
    float*       out = (float*)d_out;

    const long long P = (long long)in_sizes[2];
    const int       N = in_sizes[0] / 3;

    if (P == (long long)N * (N - 1) / 2) {
        const long long threads = (P + PPT - 1) / PPT;
        const long long grid    = (threads + BLOCK - 1) / BLOCK;
        nl_nsq_analytic4<<<(dim3)(unsigned)grid, BLOCK, 0, stream>>>(
            pos, box, out, P, N);
    } else {
        const long long grid = (P + BLOCK - 1) / BLOCK;
        nl_nsq_loadidx<<<(dim3)(unsigned)grid, BLOCK, 0, stream>>>(
            pos, box, ip, jp, out, P);
    }
}